// Round 8
// baseline (212.476 us; speedup 1.0000x reference)
//
#include <hip/hip_runtime.h>

// FprojLatentConditioned: Jacobi 3x3 SVD + bf16-MFMA MLP, fused.
// R8: barrier-free wave-stripe MLP. Each wave owns 32 batch rows and computes
// ALL 128 neurons for them (2 batch tiles x 8 neuron tiles x 4 ks) -> reads and
// writes confined to own rows -> no inter-wave hazard -> barriers 10 -> 2
// (after feature staging, before finale). Per-wave DS ops are in-order, so the
// intra-wave read->write overlap on Hbuf is safe. Features (cols 0..31) and the
// f32 layer-5 output (bytes 0..63 of each row) live inside Hbuf (own rows) --
// X0/Xout eliminated, LDS ~45KB -> ~35KB. Epilogue: packed-f32 GELU (R7).

typedef short bf16x8 __attribute__((ext_vector_type(8)));
typedef float f32x4 __attribute__((ext_vector_type(4)));
typedef float f32x2 __attribute__((ext_vector_type(2)));
typedef unsigned int u32x2 __attribute__((ext_vector_type(2)));
typedef unsigned short u16;

// ---- ws layout (bytes) ----
#define WS_L1     0          // 8 frag-rows  [ntg(8)][lane(64)] x 16B
#define WS_L234   8192       // 96 frag-rows [layer(3)][ntg(8)][ks(4)][lane(64)] x 16B
#define WS_L5     106496     // 4 frag-rows  [ks(4)][lane(64)] x 16B
#define WS_B1EFF  110592     // f32[128]
#define WS_B234   111104     // f32[128] x 3
#define WS_B5     112640     // f32[16]
#define WS_NEEDED 131072

__device__ __forceinline__ float bf2f(u16 b){
  union { unsigned int u; float f; } v; v.u = ((unsigned int)b) << 16; return v.f;
}
__device__ __forceinline__ u16 f2bf(float f){
  union { float f; unsigned int u; } v; v.f = f;
  unsigned int x = v.u;
  return (u16)((x + 0x7fffu + ((x >> 16) & 1u)) >> 16); // RNE
}
// pack two floats -> two bf16 (round-half-up; <=0.5 ulp) in one u32
__device__ __forceinline__ unsigned int pack2bf(float f0, float f1){
  union { float f; unsigned int u; } a, b; a.f = f0; b.f = f1;
  unsigned int u0 = a.u + 0x8000u;
  unsigned int u1 = b.u + 0x8000u;
#if __has_builtin(__builtin_amdgcn_perm)
  return __builtin_amdgcn_perm(u1, u0, 0x07060302u);  // D = [u1.hi : u0.hi]
#else
  return (u0 >> 16) | (u1 & 0xffff0000u);
#endif
}
template<bool B16>
__device__ __forceinline__ float ldf(const void* p, int i){
  return B16 ? bf2f(((const u16*)p)[i]) : ((const float*)p)[i];
}
template<bool B16>
__device__ __forceinline__ short ldw(const void* p, int i){  // value as bf16 bits
  return B16 ? (short)((const u16*)p)[i] : (short)f2bf(((const float*)p)[i]);
}
template<bool B16>
__device__ __forceinline__ void stf(void* p, int i, float v){
  if (B16) ((u16*)p)[i] = f2bf(v); else ((float*)p)[i] = v;
}

__device__ __forceinline__ float med3f(float x, float lo, float hi){
#if __has_builtin(__builtin_amdgcn_fmed3f)
  return __builtin_amdgcn_fmed3f(x, lo, hi);
#else
  return fminf(fmaxf(x, lo), hi);
#endif
}

// GELU on a pair + bf16 pack (packed-f32 v_pk_* forms). Phi fit at x={0.6,1.6,2.5,3.4}.
__device__ __forceinline__ unsigned int gelu2_pack(float x0, float x1){
  const f32x2 A7 = {-2.20713e-4f, -2.20713e-4f};
  const f32x2 A5 = { 5.86695e-3f,  5.86695e-3f};
  const f32x2 A3 = {-5.99485e-2f, -5.99485e-2f};
  const f32x2 A1 = { 3.969014e-1f, 3.969014e-1f};
  const f32x2 HF = { 0.5f, 0.5f};
  f32x2 xc; xc[0] = med3f(x0, -3.4f, 3.4f); xc[1] = med3f(x1, -3.4f, 3.4f);
  f32x2 s  = xc * xc;
  f32x2 g  = s * A7 + A5;
  g = s * g + A3;
  g = s * g + A1;
  f32x2 ph = xc * g + HF;
  f32x2 xin; xin[0] = x0; xin[1] = x1;
  f32x2 y = xin * ph;
  return pack2bf(y[0], y[1]);
}

__device__ __forceinline__ int sniff_bf16(const void* Fg){
  const u16* fu = (const u16*)Fg;
  int votes = 0;
  #pragma unroll
  for (int k = 0; k < 32; ++k){
    u16 h = fu[k*18];
    votes += (h >= 0x3E00 && h < 0x4000) ? 1 : 0;
  }
  return votes >= 16;
}

// ---------------- robust 3x3 SVD: Jacobi on F^T F ----------------
template<int P, int Q, int R3>
__device__ __forceinline__ void jrot(float bm[3][3], float v[3][3]){
  float bpq = bm[P][Q];
  if (fabsf(bpq) < 1e-30f) return;
  float th = (bm[Q][Q] - bm[P][P]) / (2.0f * bpq);
  float t = copysignf(1.0f, th) / (fabsf(th) + sqrtf(1.0f + th*th));
  float c = 1.0f / sqrtf(1.0f + t*t);
  float s = t * c;
  float bpp = bm[P][P] - t*bpq;
  float bqq = bm[Q][Q] + t*bpq;
  bm[P][P] = bpp; bm[Q][Q] = bqq; bm[P][Q] = 0.0f; bm[Q][P] = 0.0f;
  float bpr = bm[P][R3], bqr = bm[Q][R3];
  float npr = c*bpr - s*bqr;
  float nqr = s*bpr + c*bqr;
  bm[P][R3] = npr; bm[R3][P] = npr;
  bm[Q][R3] = nqr; bm[R3][Q] = nqr;
  #pragma unroll
  for (int i = 0; i < 3; ++i){
    float vp = v[i][P], vq = v[i][Q];
    v[i][P] = c*vp - s*vq;
    v[i][Q] = s*vp + c*vq;
  }
}

__device__ __forceinline__ void svd3(const float Fm[9],
                                     float u[3][3], float sg[3], float vt[3][3]){
  float bm[3][3];
  #pragma unroll
  for (int i = 0; i < 3; ++i)
    #pragma unroll
    for (int j = i; j < 3; ++j){
      float acc = Fm[0*3+i]*Fm[0*3+j] + Fm[1*3+i]*Fm[1*3+j] + Fm[2*3+i]*Fm[2*3+j];
      bm[i][j] = acc; bm[j][i] = acc;
    }
  float v[3][3] = {{1.f,0.f,0.f},{0.f,1.f,0.f},{0.f,0.f,1.f}};
  #pragma unroll
  for (int sweep = 0; sweep < 5; ++sweep){
    jrot<0,1,2>(bm, v);
    jrot<0,2,1>(bm, v);
    jrot<1,2,0>(bm, v);
  }
  float lam0 = bm[0][0], lam1 = bm[1][1], lam2 = bm[2][2];
  #define CSWAP(la, lb, A, Bc) if ((la) < (lb)) { float t_ = la; la = lb; lb = t_; \
    for (int i_ = 0; i_ < 3; ++i_){ float w_ = v[i_][A]; v[i_][A] = v[i_][Bc]; v[i_][Bc] = w_; } }
  CSWAP(lam0, lam1, 0, 1);
  CSWAP(lam0, lam2, 0, 2);
  CSWAP(lam1, lam2, 1, 2);
  #undef CSWAP
  float a[3][3];
  #pragma unroll
  for (int c = 0; c < 3; ++c)
    #pragma unroll
    for (int r = 0; r < 3; ++r)
      a[r][c] = Fm[r*3+0]*v[0][c] + Fm[r*3+1]*v[1][c] + Fm[r*3+2]*v[2][c];
  float s1 = sqrtf(a[0][0]*a[0][0] + a[1][0]*a[1][0] + a[2][0]*a[2][0]);
  float inv1 = 1.0f / fmaxf(s1, 1e-30f);
  u[0][0] = a[0][0]*inv1; u[1][0] = a[1][0]*inv1; u[2][0] = a[2][0]*inv1;
  float d12 = u[0][0]*a[0][1] + u[1][0]*a[1][1] + u[2][0]*a[2][1];
  float w20 = a[0][1] - d12*u[0][0], w21 = a[1][1] - d12*u[1][0], w22 = a[2][1] - d12*u[2][0];
  float s2 = sqrtf(w20*w20 + w21*w21 + w22*w22);
  float inv2 = 1.0f / fmaxf(s2, 1e-30f);
  u[0][1] = w20*inv2; u[1][1] = w21*inv2; u[2][1] = w22*inv2;
  float d13 = u[0][0]*a[0][2] + u[1][0]*a[1][2] + u[2][0]*a[2][2];
  float d23 = u[0][1]*a[0][2] + u[1][1]*a[1][2] + u[2][1]*a[2][2];
  float w30 = a[0][2] - d13*u[0][0] - d23*u[0][1];
  float w31 = a[1][2] - d13*u[1][0] - d23*u[1][1];
  float w32 = a[2][2] - d13*u[2][0] - d23*u[2][1];
  float s3 = sqrtf(w30*w30 + w31*w31 + w32*w32);
  if (s3 > 1e-12f){
    float inv3 = 1.0f / s3;
    u[0][2] = w30*inv3; u[1][2] = w31*inv3; u[2][2] = w32*inv3;
  } else {
    float c0 = u[1][0]*u[2][1] - u[2][0]*u[1][1];
    float c1 = u[2][0]*u[0][1] - u[0][0]*u[2][1];
    float c2 = u[0][0]*u[1][1] - u[1][0]*u[0][1];
    float dt = c0*a[0][2] + c1*a[1][2] + c2*a[2][2];
    float sgn = (dt < 0.0f) ? -1.0f : 1.0f;
    u[0][2] = c0*sgn; u[1][2] = c1*sgn; u[2][2] = c2*sgn;
    s3 = fabsf(dt);
  }
  sg[0] = s1; sg[1] = s2; sg[2] = s3;
  #pragma unroll
  for (int i = 0; i < 3; ++i)
    #pragma unroll
    for (int j = 0; j < 3; ++j)
      vt[i][j] = v[j][i];
}

// ---------------- prep: weights -> bf16 MFMA fragments in ws ----------------
template<bool B16>
__device__ void prep_body(
  const void* latg, const void* w1g, const void* b1g,
  const void* w2g, const void* b2g, const void* w3g, const void* b3g,
  const void* w4g, const void* b4g, const void* w5g, const void* b5g,
  const int* trajg, char* ws)
{
  const int tid = threadIdx.x, lane = tid & 63, wv = tid >> 6;
  const int quad = lane >> 4, l15 = lane & 15;
  const int blk = blockIdx.x;
  if (blk < 27){
    const int wr = blk*4 + wv;   // 0..107 wave-rows
    bf16x8 frag;
    if (wr < 8){
      const int ntg = wr;
      #pragma unroll
      for (int j = 0; j < 8; ++j)
        frag[j] = ldw<B16>(w1g, (quad*8 + j)*128 + ntg*16 + l15);
      *(bf16x8*)(ws + WS_L1 + (size_t)(wr*64 + lane)*16) = frag;
    } else if (wr < 104){
      const int idx = wr - 8, layer = idx >> 5, rem = idx & 31;
      const int ntg = rem >> 2, ks = rem & 3;
      const void* wg = (layer == 0) ? w2g : ((layer == 1) ? w3g : w4g);
      #pragma unroll
      for (int j = 0; j < 8; ++j)
        frag[j] = ldw<B16>(wg, (ks*32 + quad*8 + j)*128 + ntg*16 + l15);
      *(bf16x8*)(ws + WS_L234 + (size_t)(idx*64 + lane)*16) = frag;
    } else {
      const int ks = wr - 104;
      #pragma unroll
      for (int j = 0; j < 8; ++j)
        frag[j] = (l15 < 9) ? ldw<B16>(w5g, (ks*32 + quad*8 + j)*9 + l15) : (short)0;
      *(bf16x8*)(ws + WS_L5 + (size_t)(ks*64 + lane)*16) = frag;
    }
  } else {
    if (tid < 128){
      const int t7 = trajg[0];
      float acc = ldf<B16>(b1g, tid);
      for (int j = 0; j < 64; ++j)
        acc += ldf<B16>(latg, t7*64 + j) * ldf<B16>(w1g, (30 + j)*128 + tid);
      ((float*)(ws + WS_B1EFF))[tid] = acc;
    } else {
      const int n = tid - 128;
      ((float*)(ws + WS_B234))[0*128 + n] = ldf<B16>(b2g, n);
      ((float*)(ws + WS_B234))[1*128 + n] = ldf<B16>(b3g, n);
      ((float*)(ws + WS_B234))[2*128 + n] = ldf<B16>(b4g, n);
      if (n < 16) ((float*)(ws + WS_B5))[n] = (n < 9) ? ldf<B16>(b5g, n) : 0.0f;
    }
  }
}

__global__ __launch_bounds__(256)
void fproj_prep_kernel(
  const void* Fg, const void* latg, const void* w1g, const void* b1g,
  const void* w2g, const void* b2g, const void* w3g, const void* b3g,
  const void* w4g, const void* b4g, const void* w5g, const void* b5g,
  const int* __restrict__ trajg, char* ws)
{
  if (sniff_bf16(Fg))
    prep_body<true >(latg, w1g, b1g, w2g, b2g, w3g, b3g, w4g, b4g, w5g, b5g, trajg, ws);
  else
    prep_body<false>(latg, w1g, b1g, w2g, b2g, w3g, b3g, w4g, b4g, w5g, b5g, trajg, ws);
}

// ---------------- stripe MLP layer: wave computes all 128 neurons for its 32 rows ----
template<bool B16, bool WS>
__device__ __forceinline__ void mlp_layer_stripe(
    u16 (&Hbuf)[128][136], int wrow, int lane,
    const void* __restrict__ Wg, const void* __restrict__ bg,      // !WS
    const char* __restrict__ wsW, const float* __restrict__ bf32)  // WS
{
  const int l15 = lane & 15, quad = lane >> 4, kb = quad*8;
  f32x4 acc[2][8];
  #pragma unroll
  for (int ntg = 0; ntg < 8; ++ntg){
    const int n0 = ntg*16 + quad*4;
    f32x4 bb;
    if (WS) bb = *(const f32x4*)(bf32 + n0);
    else { bb[0]=ldf<B16>(bg,n0); bb[1]=ldf<B16>(bg,n0+1);
           bb[2]=ldf<B16>(bg,n0+2); bb[3]=ldf<B16>(bg,n0+3); }
    acc[0][ntg] = bb; acc[1][ntg] = bb;
  }
  #pragma unroll
  for (int ks = 0; ks < 4; ++ks){
    bf16x8 Af[8];
    #pragma unroll
    for (int ntg = 0; ntg < 8; ++ntg){
      if (WS) Af[ntg] = *(const bf16x8*)(wsW + (size_t)((ntg*4 + ks)*64 + lane)*16);
      else {
        bf16x8 bv;
        #pragma unroll
        for (int j = 0; j < 8; ++j)
          bv[j] = ldw<B16>(Wg, (ks*32 + kb + j)*128 + ntg*16 + l15);
        Af[ntg] = bv;
      }
    }
    #pragma unroll
    for (int mt = 0; mt < 2; ++mt){
      bf16x8 bfrag = *(const bf16x8*)&Hbuf[wrow + mt*16 + l15][ks*32 + kb];
      #pragma unroll
      for (int ntg = 0; ntg < 8; ++ntg)
        acc[mt][ntg] = __builtin_amdgcn_mfma_f32_16x16x32_bf16(Af[ntg], bfrag, acc[mt][ntg], 0,0,0);
    }
  }
  // epilogue: own rows only; per-wave DS in-order => no barrier needed
  #pragma unroll
  for (int mt = 0; mt < 2; ++mt)
    #pragma unroll
    for (int ntg = 0; ntg < 8; ++ntg){
      f32x4 c = acc[mt][ntg];
      u32x2 pk;
      pk[0] = gelu2_pack(c[0], c[1]);
      pk[1] = gelu2_pack(c[2], c[3]);
      *(u32x2*)&Hbuf[wrow + mt*16 + l15][ntg*16 + quad*4] = pk;
    }
}

// ---------------- main body ----------------
template<bool B16, bool WS>
__device__ void fproj_body(
  const void* Fg, const void* latg,
  const void* w1g, const void* b1g, const void* w2g, const void* b2g,
  const void* w3g, const void* b3g, const void* w4g, const void* b4g,
  const void* w5g, const void* b5g,
  const int* trajg, void* outg, int ntot, const char* ws,
  u16 (&Hbuf)[128][136], float* b1lds)
{
  const int tid  = threadIdx.x;
  const int lane = tid & 63;
  const int wv   = tid >> 6;
  const int l15  = lane & 15;
  const int quad = lane >> 4;
  const int kb   = quad * 8;
  const int wrow = wv * 32;             // wave-owned batch-row stripe
  const int row0 = blockIdx.x * 128;

  float Freg[9];
  float Rm[3][3];

  // ---- phase A: SVD per row (threads 0..127 -> features into Hbuf cols 0..31);
  //      b1eff (threads 128..255, !WS only) ----
  if (tid < 128){
    const int r = row0 + tid;
    float fv[32];
    if (r < ntot){
      float A0[9];
      #pragma unroll
      for (int k = 0; k < 9; ++k){ A0[k] = ldf<B16>(Fg, r*9 + k); Freg[k] = A0[k]; }
      float uu[3][3], ss[3], vvt[3][3];
      svd3(A0, uu, ss, vvt);
      #pragma unroll
      for (int i = 0; i < 3; ++i)
        #pragma unroll
        for (int j = 0; j < 3; ++j)
          Rm[i][j] = uu[i][0]*vvt[0][j] + uu[i][1]*vvt[1][j] + uu[i][2]*vvt[2][j];
      #pragma unroll
      for (int k = 0; k < 9; ++k) fv[k]    = A0[k];
      #pragma unroll
      for (int k = 0; k < 9; ++k) fv[9+k]  = uu[k/3][k%3];
      fv[18] = ss[0]; fv[19] = ss[1]; fv[20] = ss[2];
      #pragma unroll
      for (int k = 0; k < 9; ++k) fv[21+k] = vvt[k/3][k%3];
      fv[30] = 0.0f; fv[31] = 0.0f;
    } else {
      #pragma unroll
      for (int k = 0; k < 32; ++k) fv[k] = 0.0f;
      #pragma unroll
      for (int k = 0; k < 9; ++k) Freg[k] = 0.0f;
      #pragma unroll
      for (int i = 0; i < 3; ++i)
        #pragma unroll
        for (int j = 0; j < 3; ++j) Rm[i][j] = 0.0f;
    }
    #pragma unroll
    for (int q = 0; q < 4; ++q){
      u32x2 pk;
      pk[0] = pack2bf(fv[q*8+0], fv[q*8+1]);
      pk[1] = pack2bf(fv[q*8+2], fv[q*8+3]);
      *(u32x2*)&Hbuf[tid][q*8 + 0] = pk;
      pk[0] = pack2bf(fv[q*8+4], fv[q*8+5]);
      pk[1] = pack2bf(fv[q*8+6], fv[q*8+7]);
      *(u32x2*)&Hbuf[tid][q*8 + 4] = pk;
    }
  } else if (!WS){
    const int n = tid - 128;
    const int t7 = trajg[0];
    float acc = ldf<B16>(b1g, n);
    for (int j = 0; j < 64; ++j)
      acc += ldf<B16>(latg, t7*64 + j) * ldf<B16>(w1g, (30 + j)*128 + n);
    b1lds[n] = acc;
  }
  __syncthreads();   // features + b1eff visible; last barrier until the finale

  // ---- layer 1 (K=32): reads Hbuf cols 0..31 (own rows), writes cols 0..127 ----
  {
    f32x4 acc[2][8];
    #pragma unroll
    for (int ntg = 0; ntg < 8; ++ntg){
      const int n0 = ntg*16 + quad*4;
      f32x4 bb;
      if (WS) bb = *(const f32x4*)((const float*)(ws + WS_B1EFF) + n0);
      else { bb[0]=b1lds[n0]; bb[1]=b1lds[n0+1]; bb[2]=b1lds[n0+2]; bb[3]=b1lds[n0+3]; }
      acc[0][ntg] = bb; acc[1][ntg] = bb;
    }
    bf16x8 Af[8];
    #pragma unroll
    for (int ntg = 0; ntg < 8; ++ntg){
      if (WS) Af[ntg] = *(const bf16x8*)(ws + WS_L1 + (size_t)(ntg*64 + lane)*16);
      else {
        bf16x8 bv;
        #pragma unroll
        for (int j = 0; j < 8; ++j)
          bv[j] = ldw<B16>(w1g, (kb + j)*128 + ntg*16 + l15);
        Af[ntg] = bv;
      }
    }
    #pragma unroll
    for (int mt = 0; mt < 2; ++mt){
      bf16x8 bfrag = *(const bf16x8*)&Hbuf[wrow + mt*16 + l15][kb];
      #pragma unroll
      for (int ntg = 0; ntg < 8; ++ntg)
        acc[mt][ntg] = __builtin_amdgcn_mfma_f32_16x16x32_bf16(Af[ntg], bfrag, acc[mt][ntg], 0,0,0);
    }
    #pragma unroll
    for (int mt = 0; mt < 2; ++mt)
      #pragma unroll
      for (int ntg = 0; ntg < 8; ++ntg){
        f32x4 c = acc[mt][ntg];
        u32x2 pk;
        pk[0] = gelu2_pack(c[0], c[1]);
        pk[1] = gelu2_pack(c[2], c[3]);
        *(u32x2*)&Hbuf[wrow + mt*16 + l15][ntg*16 + quad*4] = pk;
      }
  }

  // ---- layers 2..4 (barrier-free) ----
  const float* bf32 = (const float*)(ws + WS_B234);
  mlp_layer_stripe<B16,WS>(Hbuf, wrow, lane, w2g, b2g, ws + WS_L234 + 0*32768, bf32 + 0*128);
  mlp_layer_stripe<B16,WS>(Hbuf, wrow, lane, w3g, b3g, ws + WS_L234 + 1*32768, bf32 + 1*128);
  mlp_layer_stripe<B16,WS>(Hbuf, wrow, lane, w4g, b4g, ws + WS_L234 + 2*32768, bf32 + 2*128);

  // ---- layer 5: 9 neurons; write f32x4 into Hbuf row bytes 0..63 (own rows) ----
  {
    f32x4 acc5[2];
    {
      f32x4 bb5;
      if (WS) bb5 = *(const f32x4*)((const float*)(ws + WS_B5) + quad*4);
      else {
        #pragma unroll
        for (int rg = 0; rg < 4; ++rg)
          bb5[rg] = (quad*4 + rg < 9) ? ldf<B16>(b5g, quad*4 + rg) : 0.0f;
      }
      acc5[0] = bb5; acc5[1] = bb5;
    }
    #pragma unroll
    for (int ks = 0; ks < 4; ++ks){
      bf16x8 W5f;
      if (WS) W5f = *(const bf16x8*)(ws + WS_L5 + (size_t)(ks*64 + lane)*16);
      else {
        bf16x8 bv;
        #pragma unroll
        for (int j = 0; j < 8; ++j)
          bv[j] = (l15 < 9) ? ldw<B16>(w5g, (ks*32 + kb + j)*9 + l15) : (short)0;
        W5f = bv;
      }
      #pragma unroll
      for (int mt = 0; mt < 2; ++mt){
        bf16x8 bfrag = *(const bf16x8*)&Hbuf[wrow + mt*16 + l15][ks*32 + kb];
        acc5[mt] = __builtin_amdgcn_mfma_f32_16x16x32_bf16(W5f, bfrag, acc5[mt], 0,0,0);
      }
    }
    #pragma unroll
    for (int mt = 0; mt < 2; ++mt)
      *(f32x4*)((float*)&Hbuf[wrow + mt*16 + l15][0] + quad*4) = acc5[mt];
  }
  __syncthreads();   // layer-5 f32 rows visible to the finale threads

  // ---- finale: out = 0.1 * R @ sym(x) + F ----
  if (tid < 128){
    const int r = row0 + tid;
    if (r < ntot){
      const float* xr = (const float*)&Hbuf[tid][0];
      float x[9];
      #pragma unroll
      for (int k = 0; k < 9; ++k) x[k] = xr[k];
      float xs[3][3];
      #pragma unroll
      for (int i = 0; i < 3; ++i)
        #pragma unroll
        for (int j = 0; j < 3; ++j)
          xs[i][j] = 0.5f*(x[i*3+j] + x[j*3+i]);
      #pragma unroll
      for (int i = 0; i < 3; ++i)
        #pragma unroll
        for (int j = 0; j < 3; ++j){
          float y = Rm[i][0]*xs[0][j] + Rm[i][1]*xs[1][j] + Rm[i][2]*xs[2][j];
          stf<B16>(outg, r*9 + i*3 + j, 0.1f*y + Freg[i*3+j]);
        }
    }
  }
}

__global__ __launch_bounds__(256, 3)
void fproj_ws_kernel(
  const void* Fg, const void* latg,
  const void* w1g, const void* b1g, const void* w2g, const void* b2g,
  const void* w3g, const void* b3g, const void* w4g, const void* b4g,
  const void* w5g, const void* b5g,
  const int* __restrict__ trajg, void* outg, int ntot, const char* ws)
{
  __shared__ alignas(16) u16 Hbuf[128][136];  // shared by both instantiations
  if (sniff_bf16(Fg))
    fproj_body<true , true>(Fg, latg, w1g, b1g, w2g, b2g, w3g, b3g, w4g, b4g,
                            w5g, b5g, trajg, outg, ntot, ws, Hbuf, nullptr);
  else
    fproj_body<false, true>(Fg, latg, w1g, b1g, w2g, b2g, w3g, b3g, w4g, b4g,
                            w5g, b5g, trajg, outg, ntot, ws, Hbuf, nullptr);
}

__global__ __launch_bounds__(256, 3)
void fproj_plain_kernel(
  const void* Fg, const void* latg,
  const void* w1g, const void* b1g, const void* w2g, const void* b2g,
  const void* w3g, const void* b3g, const void* w4g, const void* b4g,
  const void* w5g, const void* b5g,
  const int* __restrict__ trajg, void* outg, int ntot)
{
  __shared__ alignas(16) u16 Hbuf[128][136];
  __shared__ float b1lds[128];
  if (sniff_bf16(Fg))
    fproj_body<true , false>(Fg, latg, w1g, b1g, w2g, b2g, w3g, b3g, w4g, b4g,
                             w5g, b5g, trajg, outg, ntot, nullptr, Hbuf, b1lds);
  else
    fproj_body<false, false>(Fg, latg, w1g, b1g, w2g, b2g, w3g, b3g, w4g, b4g,
                             w5g, b5g, trajg, outg, ntot, nullptr, Hbuf, b1lds);
}

extern "C" void kernel_launch(void* const* d_in, const int* in_sizes, int n_in,
                              void* d_out, int out_size, void* d_ws, size_t ws_size,
                              hipStream_t stream) {
  (void)n_in; (void)out_size;
  const int n = in_sizes[0] / 9;
  dim3 grid((n + 127) / 128), block(256);
  if (ws_size >= (size_t)WS_NEEDED){
    hipLaunchKernelGGL(fproj_prep_kernel, dim3(28), block, 0, stream,
      (const void*)d_in[0],  (const void*)d_in[1],
      (const void*)d_in[2],  (const void*)d_in[3],
      (const void*)d_in[4],  (const void*)d_in[5],
      (const void*)d_in[6],  (const void*)d_in[7],
      (const void*)d_in[8],  (const void*)d_in[9],
      (const void*)d_in[10], (const void*)d_in[11],
      (const int*)d_in[12], (char*)d_ws);
    hipLaunchKernelGGL(fproj_ws_kernel, grid, block, 0, stream,
      (const void*)d_in[0],  (const void*)d_in[1],
      (const void*)d_in[2],  (const void*)d_in[3],
      (const void*)d_in[4],  (const void*)d_in[5],
      (const void*)d_in[6],  (const void*)d_in[7],
      (const void*)d_in[8],  (const void*)d_in[9],
      (const void*)d_in[10], (const void*)d_in[11],
      (const int*)d_in[12], d_out, n, (const char*)d_ws);
  } else {
    hipLaunchKernelGGL(fproj_plain_kernel, grid, block, 0, stream,
      (const void*)d_in[0],  (const void*)d_in[1],
      (const void*)d_in[2],  (const void*)d_in[3],
      (const void*)d_in[4],  (const void*)d_in[5],
      (const void*)d_in[6],  (const void*)d_in[7],
      (const void*)d_in[8],  (const void*)d_in[9],
      (const void*)d_in[10], (const void*)d_in[11],
      (const int*)d_in[12], d_out, n);
  }
}

// Round 9
// 198.586 us; speedup vs baseline: 1.0699x; 1.0699x over previous
//
#include <hip/hip_runtime.h>

// FprojLatentConditioned: Jacobi 3x3 SVD + bf16-MFMA MLP, fused.
// R9: R7 tiling (wave owns 32-neuron stripe; weight reads 1/4 per wave; 2
// barriers/layer -- proven best bench) + R8 LDS overlay (features live in Hbuf
// cols 0..31, layer-5 f32 output in Hbuf row bytes 0..63 -> no X0/Xout, LDS
// 45->34.8 KB) + __launch_bounds__(256,4) -> 4 blocks/CU (R8 showed 3 was the
// occupancy cap, not LDS). Packed-f32 GELU epilogue (R7).

typedef short bf16x8 __attribute__((ext_vector_type(8)));
typedef float f32x4 __attribute__((ext_vector_type(4)));
typedef float f32x2 __attribute__((ext_vector_type(2)));
typedef unsigned int u32x2 __attribute__((ext_vector_type(2)));
typedef unsigned short u16;

// ---- ws layout (bytes) ----
#define WS_L1     0          // 8 frag-rows  [ntg(8)][lane(64)] x 16B
#define WS_L234   8192       // 96 frag-rows [layer(3)][ntg(8)][ks(4)][lane(64)] x 16B
#define WS_L5     106496     // 4 frag-rows  [ks(4)][lane(64)] x 16B
#define WS_B1EFF  110592     // f32[128]
#define WS_B234   111104     // f32[128] x 3
#define WS_B5     112640     // f32[16]
#define WS_NEEDED 131072

__device__ __forceinline__ float bf2f(u16 b){
  union { unsigned int u; float f; } v; v.u = ((unsigned int)b) << 16; return v.f;
}
__device__ __forceinline__ u16 f2bf(float f){
  union { float f; unsigned int u; } v; v.f = f;
  unsigned int x = v.u;
  return (u16)((x + 0x7fffu + ((x >> 16) & 1u)) >> 16); // RNE
}
// pack two floats -> two bf16 (round-half-up; <=0.5 ulp) in one u32
__device__ __forceinline__ unsigned int pack2bf(float f0, float f1){
  union { float f; unsigned int u; } a, b; a.f = f0; b.f = f1;
  unsigned int u0 = a.u + 0x8000u;
  unsigned int u1 = b.u + 0x8000u;
#if __has_builtin(__builtin_amdgcn_perm)
  return __builtin_amdgcn_perm(u1, u0, 0x07060302u);  // D = [u1.hi : u0.hi]
#else
  return (u0 >> 16) | (u1 & 0xffff0000u);
#endif
}
template<bool B16>
__device__ __forceinline__ float ldf(const void* p, int i){
  return B16 ? bf2f(((const u16*)p)[i]) : ((const float*)p)[i];
}
template<bool B16>
__device__ __forceinline__ short ldw(const void* p, int i){  // value as bf16 bits
  return B16 ? (short)((const u16*)p)[i] : (short)f2bf(((const float*)p)[i]);
}
template<bool B16>
__device__ __forceinline__ void stf(void* p, int i, float v){
  if (B16) ((u16*)p)[i] = f2bf(v); else ((float*)p)[i] = v;
}

__device__ __forceinline__ float med3f(float x, float lo, float hi){
#if __has_builtin(__builtin_amdgcn_fmed3f)
  return __builtin_amdgcn_fmed3f(x, lo, hi);
#else
  return fminf(fmaxf(x, lo), hi);
#endif
}

// GELU on a pair + bf16 pack (packed-f32 v_pk_* forms). Phi fit at x={0.6,1.6,2.5,3.4}.
__device__ __forceinline__ unsigned int gelu2_pack(float x0, float x1){
  const f32x2 A7 = {-2.20713e-4f, -2.20713e-4f};
  const f32x2 A5 = { 5.86695e-3f,  5.86695e-3f};
  const f32x2 A3 = {-5.99485e-2f, -5.99485e-2f};
  const f32x2 A1 = { 3.969014e-1f, 3.969014e-1f};
  const f32x2 HF = { 0.5f, 0.5f};
  f32x2 xc; xc[0] = med3f(x0, -3.4f, 3.4f); xc[1] = med3f(x1, -3.4f, 3.4f);
  f32x2 s  = xc * xc;
  f32x2 g  = s * A7 + A5;
  g = s * g + A3;
  g = s * g + A1;
  f32x2 ph = xc * g + HF;
  f32x2 xin; xin[0] = x0; xin[1] = x1;
  f32x2 y = xin * ph;
  return pack2bf(y[0], y[1]);
}

__device__ __forceinline__ int sniff_bf16(const void* Fg){
  const u16* fu = (const u16*)Fg;
  int votes = 0;
  #pragma unroll
  for (int k = 0; k < 32; ++k){
    u16 h = fu[k*18];
    votes += (h >= 0x3E00 && h < 0x4000) ? 1 : 0;
  }
  return votes >= 16;
}

// ---------------- robust 3x3 SVD: Jacobi on F^T F ----------------
template<int P, int Q, int R3>
__device__ __forceinline__ void jrot(float bm[3][3], float v[3][3]){
  float bpq = bm[P][Q];
  if (fabsf(bpq) < 1e-30f) return;
  float th = (bm[Q][Q] - bm[P][P]) / (2.0f * bpq);
  float t = copysignf(1.0f, th) / (fabsf(th) + sqrtf(1.0f + th*th));
  float c = 1.0f / sqrtf(1.0f + t*t);
  float s = t * c;
  float bpp = bm[P][P] - t*bpq;
  float bqq = bm[Q][Q] + t*bpq;
  bm[P][P] = bpp; bm[Q][Q] = bqq; bm[P][Q] = 0.0f; bm[Q][P] = 0.0f;
  float bpr = bm[P][R3], bqr = bm[Q][R3];
  float npr = c*bpr - s*bqr;
  float nqr = s*bpr + c*bqr;
  bm[P][R3] = npr; bm[R3][P] = npr;
  bm[Q][R3] = nqr; bm[R3][Q] = nqr;
  #pragma unroll
  for (int i = 0; i < 3; ++i){
    float vp = v[i][P], vq = v[i][Q];
    v[i][P] = c*vp - s*vq;
    v[i][Q] = s*vp + c*vq;
  }
}

__device__ __forceinline__ void svd3(const float Fm[9],
                                     float u[3][3], float sg[3], float vt[3][3]){
  float bm[3][3];
  #pragma unroll
  for (int i = 0; i < 3; ++i)
    #pragma unroll
    for (int j = i; j < 3; ++j){
      float acc = Fm[0*3+i]*Fm[0*3+j] + Fm[1*3+i]*Fm[1*3+j] + Fm[2*3+i]*Fm[2*3+j];
      bm[i][j] = acc; bm[j][i] = acc;
    }
  float v[3][3] = {{1.f,0.f,0.f},{0.f,1.f,0.f},{0.f,0.f,1.f}};
  #pragma unroll
  for (int sweep = 0; sweep < 5; ++sweep){
    jrot<0,1,2>(bm, v);
    jrot<0,2,1>(bm, v);
    jrot<1,2,0>(bm, v);
  }
  float lam0 = bm[0][0], lam1 = bm[1][1], lam2 = bm[2][2];
  #define CSWAP(la, lb, A, Bc) if ((la) < (lb)) { float t_ = la; la = lb; lb = t_; \
    for (int i_ = 0; i_ < 3; ++i_){ float w_ = v[i_][A]; v[i_][A] = v[i_][Bc]; v[i_][Bc] = w_; } }
  CSWAP(lam0, lam1, 0, 1);
  CSWAP(lam0, lam2, 0, 2);
  CSWAP(lam1, lam2, 1, 2);
  #undef CSWAP
  float a[3][3];
  #pragma unroll
  for (int c = 0; c < 3; ++c)
    #pragma unroll
    for (int r = 0; r < 3; ++r)
      a[r][c] = Fm[r*3+0]*v[0][c] + Fm[r*3+1]*v[1][c] + Fm[r*3+2]*v[2][c];
  float s1 = sqrtf(a[0][0]*a[0][0] + a[1][0]*a[1][0] + a[2][0]*a[2][0]);
  float inv1 = 1.0f / fmaxf(s1, 1e-30f);
  u[0][0] = a[0][0]*inv1; u[1][0] = a[1][0]*inv1; u[2][0] = a[2][0]*inv1;
  float d12 = u[0][0]*a[0][1] + u[1][0]*a[1][1] + u[2][0]*a[2][1];
  float w20 = a[0][1] - d12*u[0][0], w21 = a[1][1] - d12*u[1][0], w22 = a[2][1] - d12*u[2][0];
  float s2 = sqrtf(w20*w20 + w21*w21 + w22*w22);
  float inv2 = 1.0f / fmaxf(s2, 1e-30f);
  u[0][1] = w20*inv2; u[1][1] = w21*inv2; u[2][1] = w22*inv2;
  float d13 = u[0][0]*a[0][2] + u[1][0]*a[1][2] + u[2][0]*a[2][2];
  float d23 = u[0][1]*a[0][2] + u[1][1]*a[1][2] + u[2][1]*a[2][2];
  float w30 = a[0][2] - d13*u[0][0] - d23*u[0][1];
  float w31 = a[1][2] - d13*u[1][0] - d23*u[1][1];
  float w32 = a[2][2] - d13*u[2][0] - d23*u[2][1];
  float s3 = sqrtf(w30*w30 + w31*w31 + w32*w32);
  if (s3 > 1e-12f){
    float inv3 = 1.0f / s3;
    u[0][2] = w30*inv3; u[1][2] = w31*inv3; u[2][2] = w32*inv3;
  } else {
    float c0 = u[1][0]*u[2][1] - u[2][0]*u[1][1];
    float c1 = u[2][0]*u[0][1] - u[0][0]*u[2][1];
    float c2 = u[0][0]*u[1][1] - u[1][0]*u[0][1];
    float dt = c0*a[0][2] + c1*a[1][2] + c2*a[2][2];
    float sgn = (dt < 0.0f) ? -1.0f : 1.0f;
    u[0][2] = c0*sgn; u[1][2] = c1*sgn; u[2][2] = c2*sgn;
    s3 = fabsf(dt);
  }
  sg[0] = s1; sg[1] = s2; sg[2] = s3;
  #pragma unroll
  for (int i = 0; i < 3; ++i)
    #pragma unroll
    for (int j = 0; j < 3; ++j)
      vt[i][j] = v[j][i];
}

// ---------------- prep: weights -> bf16 MFMA fragments in ws ----------------
template<bool B16>
__device__ void prep_body(
  const void* latg, const void* w1g, const void* b1g,
  const void* w2g, const void* b2g, const void* w3g, const void* b3g,
  const void* w4g, const void* b4g, const void* w5g, const void* b5g,
  const int* trajg, char* ws)
{
  const int tid = threadIdx.x, lane = tid & 63, wv = tid >> 6;
  const int quad = lane >> 4, l15 = lane & 15;
  const int blk = blockIdx.x;
  if (blk < 27){
    const int wr = blk*4 + wv;   // 0..107 wave-rows
    bf16x8 frag;
    if (wr < 8){
      const int ntg = wr;
      #pragma unroll
      for (int j = 0; j < 8; ++j)
        frag[j] = ldw<B16>(w1g, (quad*8 + j)*128 + ntg*16 + l15);
      *(bf16x8*)(ws + WS_L1 + (size_t)(wr*64 + lane)*16) = frag;
    } else if (wr < 104){
      const int idx = wr - 8, layer = idx >> 5, rem = idx & 31;
      const int ntg = rem >> 2, ks = rem & 3;
      const void* wg = (layer == 0) ? w2g : ((layer == 1) ? w3g : w4g);
      #pragma unroll
      for (int j = 0; j < 8; ++j)
        frag[j] = ldw<B16>(wg, (ks*32 + quad*8 + j)*128 + ntg*16 + l15);
      *(bf16x8*)(ws + WS_L234 + (size_t)(idx*64 + lane)*16) = frag;
    } else {
      const int ks = wr - 104;
      #pragma unroll
      for (int j = 0; j < 8; ++j)
        frag[j] = (l15 < 9) ? ldw<B16>(w5g, (ks*32 + quad*8 + j)*9 + l15) : (short)0;
      *(bf16x8*)(ws + WS_L5 + (size_t)(ks*64 + lane)*16) = frag;
    }
  } else {
    if (tid < 128){
      const int t7 = trajg[0];
      float acc = ldf<B16>(b1g, tid);
      for (int j = 0; j < 64; ++j)
        acc += ldf<B16>(latg, t7*64 + j) * ldf<B16>(w1g, (30 + j)*128 + tid);
      ((float*)(ws + WS_B1EFF))[tid] = acc;
    } else {
      const int n = tid - 128;
      ((float*)(ws + WS_B234))[0*128 + n] = ldf<B16>(b2g, n);
      ((float*)(ws + WS_B234))[1*128 + n] = ldf<B16>(b3g, n);
      ((float*)(ws + WS_B234))[2*128 + n] = ldf<B16>(b4g, n);
      if (n < 16) ((float*)(ws + WS_B5))[n] = (n < 9) ? ldf<B16>(b5g, n) : 0.0f;
    }
  }
}

__global__ __launch_bounds__(256)
void fproj_prep_kernel(
  const void* Fg, const void* latg, const void* w1g, const void* b1g,
  const void* w2g, const void* b2g, const void* w3g, const void* b3g,
  const void* w4g, const void* b4g, const void* w5g, const void* b5g,
  const int* __restrict__ trajg, char* ws)
{
  if (sniff_bf16(Fg))
    prep_body<true >(latg, w1g, b1g, w2g, b2g, w3g, b3g, w4g, b4g, w5g, b5g, trajg, ws);
  else
    prep_body<false>(latg, w1g, b1g, w2g, b2g, w3g, b3g, w4g, b4g, w5g, b5g, trajg, ws);
}

// ---------------- MFMA MLP layer (R7 tiling: wave owns 32 neurons x 128 rows) ----
template<bool B16, bool WS>
__device__ __forceinline__ void mlp_layer128(
    u16 (&Hbuf)[128][136],
    const void* __restrict__ Wg, const void* __restrict__ bg,      // !WS sources
    const char* __restrict__ wsW, const float* __restrict__ bf32,  // WS sources
    int wv, int lane)
{
  const int l15  = lane & 15;
  const int quad = lane >> 4;
  const int kb   = quad * 8;
  f32x4 bb[2];
  #pragma unroll
  for (int nt = 0; nt < 2; ++nt){
    const int n0 = wv*32 + nt*16 + quad*4;
    if (WS) bb[nt] = *(const f32x4*)(bf32 + n0);
    else { bb[nt][0]=ldf<B16>(bg,n0); bb[nt][1]=ldf<B16>(bg,n0+1);
           bb[nt][2]=ldf<B16>(bg,n0+2); bb[nt][3]=ldf<B16>(bg,n0+3); }
  }
  bf16x8 Wf[2][4];   // A-operand: W^T[m=neuron][k]
  #pragma unroll
  for (int nt = 0; nt < 2; ++nt){
    const int ntg = wv*2 + nt;
    #pragma unroll
    for (int ks = 0; ks < 4; ++ks){
      if (WS){
        Wf[nt][ks] = *(const bf16x8*)(wsW + (size_t)((ntg*4 + ks)*64 + lane)*16);
      } else {
        bf16x8 bv;
        #pragma unroll
        for (int j = 0; j < 8; ++j)
          bv[j] = ldw<B16>(Wg, (ks*32 + kb + j)*128 + ntg*16 + l15);
        Wf[nt][ks] = bv;
      }
    }
  }
  f32x4 acc[8][2];
  #pragma unroll
  for (int mt = 0; mt < 8; ++mt){
    const u16* hp = &Hbuf[mt*16 + l15][kb];   // B-operand: Act^T[k][batch]
    bf16x8 a0 = *(const bf16x8*)(hp);
    bf16x8 a1 = *(const bf16x8*)(hp + 32);
    bf16x8 a2 = *(const bf16x8*)(hp + 64);
    bf16x8 a3 = *(const bf16x8*)(hp + 96);
    #pragma unroll
    for (int nt = 0; nt < 2; ++nt){
      f32x4 c = bb[nt];
      c = __builtin_amdgcn_mfma_f32_16x16x32_bf16(Wf[nt][0], a0, c, 0,0,0);
      c = __builtin_amdgcn_mfma_f32_16x16x32_bf16(Wf[nt][1], a1, c, 0,0,0);
      c = __builtin_amdgcn_mfma_f32_16x16x32_bf16(Wf[nt][2], a2, c, 0,0,0);
      c = __builtin_amdgcn_mfma_f32_16x16x32_bf16(Wf[nt][3], a3, c, 0,0,0);
      acc[mt][nt] = c;
    }
  }
  __syncthreads();  // WAR: all waves done reading Hbuf
  #pragma unroll
  for (int nt = 0; nt < 2; ++nt){
    const int n0 = wv*32 + nt*16 + quad*4;   // 4 consecutive neurons
    #pragma unroll
    for (int mt = 0; mt < 8; ++mt){
      f32x4 c = acc[mt][nt];
      u32x2 pk;
      pk[0] = gelu2_pack(c[0], c[1]);
      pk[1] = gelu2_pack(c[2], c[3]);
      *(u32x2*)&Hbuf[mt*16 + l15][n0] = pk;   // one ds_write_b64
    }
  }
  __syncthreads();
}

// ---------------- main body ----------------
template<bool B16, bool WS>
__device__ void fproj_body(
  const void* Fg, const void* latg,
  const void* w1g, const void* b1g, const void* w2g, const void* b2g,
  const void* w3g, const void* b3g, const void* w4g, const void* b4g,
  const void* w5g, const void* b5g,
  const int* trajg, void* outg, int ntot, const char* ws,
  u16 (&Hbuf)[128][136], float* b1lds)
{
  const int tid  = threadIdx.x;
  const int lane = tid & 63;
  const int wv   = tid >> 6;
  const int l15  = lane & 15;
  const int quad = lane >> 4;
  const int kb   = quad * 8;
  const int row0 = blockIdx.x * 128;

  float Freg[9];
  float Rm[3][3];

  // preload layer-1 W fragments (A-operand); latency overlaps SVD
  bf16x8 Wf1[2];
  #pragma unroll
  for (int nt = 0; nt < 2; ++nt){
    const int ntg = wv*2 + nt;
    if (WS){
      Wf1[nt] = *(const bf16x8*)(ws + WS_L1 + (size_t)(ntg*64 + lane)*16);
    } else {
      bf16x8 bv;
      #pragma unroll
      for (int j = 0; j < 8; ++j)
        bv[j] = ldw<B16>(w1g, (kb + j)*128 + ntg*16 + l15);
      Wf1[nt] = bv;
    }
  }

  // ---- phase A: SVD per row (threads 0..127 -> features into Hbuf cols 0..31);
  //      b1eff (threads 128..255, !WS only) ----
  if (tid < 128){
    const int r = row0 + tid;
    float fv[32];
    if (r < ntot){
      float A0[9];
      #pragma unroll
      for (int k = 0; k < 9; ++k){ A0[k] = ldf<B16>(Fg, r*9 + k); Freg[k] = A0[k]; }
      float uu[3][3], ss[3], vvt[3][3];
      svd3(A0, uu, ss, vvt);
      #pragma unroll
      for (int i = 0; i < 3; ++i)
        #pragma unroll
        for (int j = 0; j < 3; ++j)
          Rm[i][j] = uu[i][0]*vvt[0][j] + uu[i][1]*vvt[1][j] + uu[i][2]*vvt[2][j];
      #pragma unroll
      for (int k = 0; k < 9; ++k) fv[k]    = A0[k];
      #pragma unroll
      for (int k = 0; k < 9; ++k) fv[9+k]  = uu[k/3][k%3];
      fv[18] = ss[0]; fv[19] = ss[1]; fv[20] = ss[2];
      #pragma unroll
      for (int k = 0; k < 9; ++k) fv[21+k] = vvt[k/3][k%3];
      fv[30] = 0.0f; fv[31] = 0.0f;
    } else {
      #pragma unroll
      for (int k = 0; k < 32; ++k) fv[k] = 0.0f;
      #pragma unroll
      for (int k = 0; k < 9; ++k) Freg[k] = 0.0f;
      #pragma unroll
      for (int i = 0; i < 3; ++i)
        #pragma unroll
        for (int j = 0; j < 3; ++j) Rm[i][j] = 0.0f;
    }
    #pragma unroll
    for (int q = 0; q < 4; ++q){
      u32x2 pk;
      pk[0] = pack2bf(fv[q*8+0], fv[q*8+1]);
      pk[1] = pack2bf(fv[q*8+2], fv[q*8+3]);
      *(u32x2*)&Hbuf[tid][q*8 + 0] = pk;
      pk[0] = pack2bf(fv[q*8+4], fv[q*8+5]);
      pk[1] = pack2bf(fv[q*8+6], fv[q*8+7]);
      *(u32x2*)&Hbuf[tid][q*8 + 4] = pk;
    }
  } else if (!WS){
    const int n = tid - 128;
    const int t7 = trajg[0];
    float acc = ldf<B16>(b1g, n);
    for (int j = 0; j < 64; ++j)
      acc += ldf<B16>(latg, t7*64 + j) * ldf<B16>(w1g, (30 + j)*128 + n);
    b1lds[n] = acc;
  }
  __syncthreads();

  // ---- layer 1: reads Hbuf cols 0..31 (features), writes cols 0..127 ----
  {
    f32x4 bb[2];
    #pragma unroll
    for (int nt = 0; nt < 2; ++nt){
      const int n0 = wv*32 + nt*16 + quad*4;
      if (WS) bb[nt] = *(const f32x4*)((const float*)(ws + WS_B1EFF) + n0);
      else { bb[nt][0]=b1lds[n0]; bb[nt][1]=b1lds[n0+1]; bb[nt][2]=b1lds[n0+2]; bb[nt][3]=b1lds[n0+3]; }
    }
    f32x4 acc[8][2];
    #pragma unroll
    for (int mt = 0; mt < 8; ++mt){
      bf16x8 av = *(const bf16x8*)&Hbuf[mt*16 + l15][kb];
      #pragma unroll
      for (int nt = 0; nt < 2; ++nt){
        f32x4 c = bb[nt];
        c = __builtin_amdgcn_mfma_f32_16x16x32_bf16(Wf1[nt], av, c, 0,0,0);
        acc[mt][nt] = c;
      }
    }
    __syncthreads();  // feature reads done before overwrite (WAR)
    #pragma unroll
    for (int nt = 0; nt < 2; ++nt){
      const int n0 = wv*32 + nt*16 + quad*4;
      #pragma unroll
      for (int mt = 0; mt < 8; ++mt){
        f32x4 c = acc[mt][nt];
        u32x2 pk;
        pk[0] = gelu2_pack(c[0], c[1]);
        pk[1] = gelu2_pack(c[2], c[3]);
        *(u32x2*)&Hbuf[mt*16 + l15][n0] = pk;
      }
    }
  }
  __syncthreads();

  // ---- layers 2..4 ----
  const float* bf32 = (const float*)(ws + WS_B234);
  mlp_layer128<B16,WS>(Hbuf, w2g, b2g, ws + WS_L234 + 0*32768, bf32 + 0*128, wv, lane);
  mlp_layer128<B16,WS>(Hbuf, w3g, b3g, ws + WS_L234 + 1*32768, bf32 + 1*128, wv, lane);
  mlp_layer128<B16,WS>(Hbuf, w4g, b4g, ws + WS_L234 + 2*32768, bf32 + 2*128, wv, lane);

  // ---- layer 5: wave handles its own 32 rows; f32x4 into Hbuf row bytes 0..63 ----
  {
    bf16x8 W5f[4];
    #pragma unroll
    for (int ks = 0; ks < 4; ++ks){
      if (WS){
        W5f[ks] = *(const bf16x8*)(ws + WS_L5 + (size_t)(ks*64 + lane)*16);
      } else {
        bf16x8 bv;
        #pragma unroll
        for (int j = 0; j < 8; ++j)
          bv[j] = (l15 < 9) ? ldw<B16>(w5g, (ks*32 + kb + j)*9 + l15) : (short)0;
        W5f[ks] = bv;
      }
    }
    f32x4 bb5;
    if (WS) bb5 = *(const f32x4*)((const float*)(ws + WS_B5) + quad*4);
    else {
      #pragma unroll
      for (int rg = 0; rg < 4; ++rg)
        bb5[rg] = (quad*4 + rg < 9) ? ldf<B16>(b5g, quad*4 + rg) : 0.0f;
    }
    #pragma unroll
    for (int t = 0; t < 2; ++t){
      const int mt = wv*2 + t;    // own rows
      const u16* hp = &Hbuf[mt*16 + l15][kb];
      bf16x8 a0 = *(const bf16x8*)(hp);
      bf16x8 a1 = *(const bf16x8*)(hp + 32);
      bf16x8 a2 = *(const bf16x8*)(hp + 64);
      bf16x8 a3 = *(const bf16x8*)(hp + 96);
      f32x4 c = bb5;
      c = __builtin_amdgcn_mfma_f32_16x16x32_bf16(W5f[0], a0, c, 0,0,0);
      c = __builtin_amdgcn_mfma_f32_16x16x32_bf16(W5f[1], a1, c, 0,0,0);
      c = __builtin_amdgcn_mfma_f32_16x16x32_bf16(W5f[2], a2, c, 0,0,0);
      c = __builtin_amdgcn_mfma_f32_16x16x32_bf16(W5f[3], a3, c, 0,0,0);
      // intra-wave WAR on own rows: per-wave DS ops are in-order -> safe
      *(f32x4*)((float*)&Hbuf[mt*16 + l15][0] + quad*4) = c;
    }
  }
  __syncthreads();

  // ---- finale: out = 0.1 * R @ sym(x) + F ----
  if (tid < 128){
    const int r = row0 + tid;
    if (r < ntot){
      const float* xr = (const float*)&Hbuf[tid][0];
      float x[9];
      #pragma unroll
      for (int k = 0; k < 9; ++k) x[k] = xr[k];
      float xs[3][3];
      #pragma unroll
      for (int i = 0; i < 3; ++i)
        #pragma unroll
        for (int j = 0; j < 3; ++j)
          xs[i][j] = 0.5f*(x[i*3+j] + x[j*3+i]);
      #pragma unroll
      for (int i = 0; i < 3; ++i)
        #pragma unroll
        for (int j = 0; j < 3; ++j){
          float y = Rm[i][0]*xs[0][j] + Rm[i][1]*xs[1][j] + Rm[i][2]*xs[2][j];
          stf<B16>(outg, r*9 + i*3 + j, 0.1f*y + Freg[i*3+j]);
        }
    }
  }
}

__global__ __launch_bounds__(256, 4)
void fproj_ws_kernel(
  const void* Fg, const void* latg,
  const void* w1g, const void* b1g, const void* w2g, const void* b2g,
  const void* w3g, const void* b3g, const void* w4g, const void* b4g,
  const void* w5g, const void* b5g,
  const int* __restrict__ trajg, void* outg, int ntot, const char* ws)
{
  __shared__ alignas(16) u16 Hbuf[128][136];  // shared by both instantiations
  if (sniff_bf16(Fg))
    fproj_body<true , true>(Fg, latg, w1g, b1g, w2g, b2g, w3g, b3g, w4g, b4g,
                            w5g, b5g, trajg, outg, ntot, ws, Hbuf, nullptr);
  else
    fproj_body<false, true>(Fg, latg, w1g, b1g, w2g, b2g, w3g, b3g, w4g, b4g,
                            w5g, b5g, trajg, outg, ntot, ws, Hbuf, nullptr);
}

__global__ __launch_bounds__(256, 4)
void fproj_plain_kernel(
  const void* Fg, const void* latg,
  const void* w1g, const void* b1g, const void* w2g, const void* b2g,
  const void* w3g, const void* b3g, const void* w4g, const void* b4g,
  const void* w5g, const void* b5g,
  const int* __restrict__ trajg, void* outg, int ntot)
{
  __shared__ alignas(16) u16 Hbuf[128][136];
  __shared__ float b1lds[128];
  if (sniff_bf16(Fg))
    fproj_body<true , false>(Fg, latg, w1g, b1g, w2g, b2g, w3g, b3g, w4g, b4g,
                             w5g, b5g, trajg, outg, ntot, nullptr, Hbuf, b1lds);
  else
    fproj_body<false, false>(Fg, latg, w1g, b1g, w2g, b2g, w3g, b3g, w4g, b4g,
                             w5g, b5g, trajg, outg, ntot, nullptr, Hbuf, b1lds);
}

extern "C" void kernel_launch(void* const* d_in, const int* in_sizes, int n_in,
                              void* d_out, int out_size, void* d_ws, size_t ws_size,
                              hipStream_t stream) {
  (void)n_in; (void)out_size;
  const int n = in_sizes[0] / 9;
  dim3 grid((n + 127) / 128), block(256);
  if (ws_size >= (size_t)WS_NEEDED){
    hipLaunchKernelGGL(fproj_prep_kernel, dim3(28), block, 0, stream,
      (const void*)d_in[0],  (const void*)d_in[1],
      (const void*)d_in[2],  (const void*)d_in[3],
      (const void*)d_in[4],  (const void*)d_in[5],
      (const void*)d_in[6],  (const void*)d_in[7],
      (const void*)d_in[8],  (const void*)d_in[9],
      (const void*)d_in[10], (const void*)d_in[11],
      (const int*)d_in[12], (char*)d_ws);
    hipLaunchKernelGGL(fproj_ws_kernel, grid, block, 0, stream,
      (const void*)d_in[0],  (const void*)d_in[1],
      (const void*)d_in[2],  (const void*)d_in[3],
      (const void*)d_in[4],  (const void*)d_in[5],
      (const void*)d_in[6],  (const void*)d_in[7],
      (const void*)d_in[8],  (const void*)d_in[9],
      (const void*)d_in[10], (const void*)d_in[11],
      (const int*)d_in[12], d_out, n, (const char*)d_ws);
  } else {
    hipLaunchKernelGGL(fproj_plain_kernel, grid, block, 0, stream,
      (const void*)d_in[0],  (const void*)d_in[1],
      (const void*)d_in[2],  (const void*)d_in[3],
      (const void*)d_in[4],  (const void*)d_in[5],
      (const void*)d_in[6],  (const void*)d_in[7],
      (const void*)d_in[8],  (const void*)d_in[9],
      (const void*)d_in[10], (const void*)d_in[11],
      (const int*)d_in[12], d_out, n);
  }
}